// Round 3
// baseline (2207.426 us; speedup 1.0000x reference)
//
#include <hip/hip_runtime.h>

#define N_NODES 100000
#define N_EDGES 1600000
#define NB 64
#define NI 64
#define EI 32
#define GI 32
#define NO 32
#define EO 32
#define GO 32
#define HH 3
#define HNO 96   /* H*NO */
#define NEG 0.2f

// ---------------- K0: xl = x@W_l + b_l, xr = x@W_r + b_r  [N,96] each ----------------
__global__ __launch_bounds__(256) void k0_node_transform(
    const float* __restrict__ x, const float* __restrict__ W_l, const float* __restrict__ b_l,
    const float* __restrict__ W_r, const float* __restrict__ b_r,
    float* __restrict__ xl, float* __restrict__ xr, int niters)
{
    __shared__ float sWl[NI * HNO];   // 24 KB
    __shared__ float sWr[NI * HNO];   // 24 KB
    __shared__ float sx[8][NI];       // 2 KB
    int t = threadIdx.x;
    for (int f = t; f < NI * HNO; f += 256) { sWl[f] = W_l[f]; sWr[f] = W_r[f]; }
    __syncthreads();
    int k = t & 31, ni = t >> 5;
    float bl0 = b_l[k], bl1 = b_l[k + 32], bl2 = b_l[k + 64];
    float br0 = b_r[k], br1 = b_r[k + 32], br2 = b_r[k + 64];
    for (int it = 0; it < niters; ++it) {
        long g = (long)blockIdx.x + (long)it * gridDim.x;
        long n = g * 8 + ni;
        long nc = (n < N_NODES) ? n : 0;
        sx[ni][k]      = x[nc * NI + k];
        sx[ni][k + 32] = x[nc * NI + k + 32];
        __syncthreads();
        float al0 = bl0, al1 = bl1, al2 = bl2;
        float ar0 = br0, ar1 = br1, ar2 = br2;
        #pragma unroll 8
        for (int i = 0; i < NI; ++i) {
            float xv = sx[ni][i];
            al0 += xv * sWl[i * HNO + k];
            al1 += xv * sWl[i * HNO + k + 32];
            al2 += xv * sWl[i * HNO + k + 64];
            ar0 += xv * sWr[i * HNO + k];
            ar1 += xv * sWr[i * HNO + k + 32];
            ar2 += xv * sWr[i * HNO + k + 64];
        }
        if (n < N_NODES) {
            xl[n * HNO + k]      = al0; xl[n * HNO + k + 32] = al1; xl[n * HNO + k + 64] = al2;
            xr[n * HNO + k]      = ar0; xr[n * HNO + k + 32] = ar1; xr[n * HNO + k + 64] = ar2;
        }
        __syncthreads();
    }
}

// ---------------- K_hist: cnt[dst]++ ----------------
__global__ __launch_bounds__(256) void k_hist(const int* __restrict__ eidx, int* __restrict__ cnt)
{
    long i = (long)blockIdx.x * 256 + threadIdx.x;
    long stride = (long)gridDim.x * 256;
    for (; i < N_EDGES; i += stride)
        atomicAdd(&cnt[eidx[N_EDGES + i]], 1);
}

// ---------------- K_scan: exclusive scan of cnt -> off (N+1) and cursor ----------------
__global__ __launch_bounds__(1024) void k_scan(const int* __restrict__ cnt,
                                               int* __restrict__ off, int* __restrict__ cursor)
{
    __shared__ int ssum[1024];
    const int CH = (N_NODES + 1023) / 1024;   // 98
    int t = threadIdx.x;
    int c0 = t * CH;
    int c1 = c0 + CH; if (c1 > N_NODES) c1 = N_NODES;
    int s = 0;
    for (int i = c0; i < c1; ++i) s += cnt[i];
    ssum[t] = s;
    __syncthreads();
    // Hillis-Steele inclusive scan
    for (int ofs = 1; ofs < 1024; ofs <<= 1) {
        int v = (t >= ofs) ? ssum[t - ofs] : 0;
        __syncthreads();
        ssum[t] += v;
        __syncthreads();
    }
    int run = ssum[t] - s;    // exclusive base for this chunk
    for (int i = c0; i < c1; ++i) {
        off[i] = run; cursor[i] = run;
        run += cnt[i];
    }
    if (t == 1023) off[N_NODES] = ssum[1023];
}

// ---------------- K_scatter: CSR edge-id list grouped by dst ----------------
__global__ __launch_bounds__(256) void k_scatter(const int* __restrict__ eidx,
                                                 int* __restrict__ cursor, int* __restrict__ eids_p)
{
    long i = (long)blockIdx.x * 256 + threadIdx.x;
    long stride = (long)gridDim.x * 256;
    for (; i < N_EDGES; i += stride) {
        int d = eidx[N_EDGES + i];
        int pos = atomicAdd(&cursor[d], 1);
        eids_p[pos] = (int)i;
    }
}

// ---------------- K1a: fused edge pass (NO dst-scatter atomics) ----------------
// e = relu([x[src], ea] @ W_edge + b_edge)           -> write e_out
// h = xl[src] + xr[dst] + e @ W_e
// logit_h = sum_k leakyrelu(h)*att ; ex = exp(logit)  (no max-subtraction: logits O(1))
// write exv4[e] = {ex0, ex1, ex2, src_as_bits}  (coalesced 16B)
__global__ __launch_bounds__(256) void k1a_edge(
    const float* __restrict__ x, const float* __restrict__ ea,
    const float* __restrict__ W_edge, const float* __restrict__ b_edge,
    const float* __restrict__ W_e, const float* __restrict__ att,
    const int* __restrict__ eidx,   // [2, E]
    const float* __restrict__ xl, const float* __restrict__ xr,
    float* __restrict__ e_out, float4* __restrict__ exv4,
    int niters)
{
    __shared__ float sWedge[96 * 32];  // 12 KB
    __shared__ float sWe[32 * 96];     // 12 KB
    __shared__ float sAtt[96];
    __shared__ float sIn[8][96];       // 3 KB
    __shared__ float sEo[8][32];       // 1 KB
    int t = threadIdx.x;
    for (int f = t; f < 96 * 32; f += 256) { sWedge[f] = W_edge[f]; sWe[f] = W_e[f]; }
    if (t < 96) sAtt[t] = att[t];
    __syncthreads();
    int k = t & 31, eg = t >> 5;    // 8 edges per block-iteration
    float be = b_edge[k];
    for (int it = 0; it < niters; ++it) {
        long e0 = ((long)blockIdx.x + (long)it * gridDim.x) * 8;
        // --- P0: stage inputs: 8 edges x 96 features ---
        #pragma unroll
        for (int r = 0; r < 3; ++r) {
            int f = r * 256 + t;
            int ei2 = f / 96;
            int i = f - ei2 * 96;
            long e = e0 + ei2;
            long ec = (e < N_EDGES) ? e : 0;
            int s = eidx[ec];
            float v = (i < NI) ? x[(long)s * NI + i] : ea[ec * EI + (i - NI)];
            sIn[ei2][i] = v;
        }
        __syncthreads();
        // --- P1: edge MLP ---
        long e = e0 + eg;
        bool valid = (e < N_EDGES);
        long ec = valid ? e : 0;
        float acc = be;
        #pragma unroll 8
        for (int i = 0; i < 96; ++i) acc += sIn[eg][i] * sWedge[i * 32 + k];
        acc = fmaxf(acc, 0.f);
        sEo[eg][k] = acc;
        if (valid) e_out[ec * EO + k] = acc;
        __syncthreads();
        // --- P2: h, logits, exp ---
        int s = eidx[ec];
        int d = eidx[N_EDGES + ec];
        float xlv0 = xl[(long)s * HNO + k];
        float xlv1 = xl[(long)s * HNO + k + 32];
        float xlv2 = xl[(long)s * HNO + k + 64];
        float h0 = xlv0 + xr[(long)d * HNO + k];
        float h1 = xlv1 + xr[(long)d * HNO + k + 32];
        float h2 = xlv2 + xr[(long)d * HNO + k + 64];
        #pragma unroll 8
        for (int i = 0; i < 32; ++i) {
            float eo = sEo[eg][i];
            h0 += eo * sWe[i * 96 + k];
            h1 += eo * sWe[i * 96 + 32 + k];
            h2 += eo * sWe[i * 96 + 64 + k];
        }
        float p0 = (h0 > 0.f ? h0 : NEG * h0) * sAtt[k];
        float p1 = (h1 > 0.f ? h1 : NEG * h1) * sAtt[32 + k];
        float p2 = (h2 > 0.f ? h2 : NEG * h2) * sAtt[64 + k];
        #pragma unroll
        for (int m = 1; m <= 16; m <<= 1) {
            p0 += __shfl_xor(p0, m);
            p1 += __shfl_xor(p1, m);
            p2 += __shfl_xor(p2, m);
        }
        if (valid && k == 0) {
            exv4[ec] = make_float4(__expf(p0), __expf(p1), __expf(p2), __int_as_float(s));
        }
        __syncthreads();
    }
}

// ---------------- K1b: per-node gather (no atomics) + fused node_mlp_2 ----------------
// One wave (64 lanes) per node. Each lane prefetches its OWN edge's exv4 once per
// 64-edge chunk (64 independent loads in flight); the inner loop broadcasts
// (ex0,ex1,ex2,src) via __shfl. Loop trip count is UNIFORM across the wave so every
// __shfl executes with all 64 lanes active (the j<cnt guard only gates accumulation).
__global__ __launch_bounds__(256) void k1b_gather(
    const float* __restrict__ xl, const float4* __restrict__ exv4,
    const int* __restrict__ eids_p, const int* __restrict__ off,
    const float* __restrict__ bias_gat, const float* __restrict__ glob,
    const int* __restrict__ batch, const float* __restrict__ W_n2,
    const float* __restrict__ b_n2, float* __restrict__ x_new)
{
    __shared__ float sW[128 * 32];   // 16 KB
    int t = threadIdx.x;
    for (int f = t; f < 128 * 32; f += 256) sW[f] = W_n2[f];
    __syncthreads();
    int wave = t >> 6;       // 4 waves per block
    int lane = t & 63;
    int k = lane & 31, half = lane >> 5;
    long n = (long)blockIdx.x * 4 + wave;
    if (n >= N_NODES) return;

    int lo = off[n], hi = off[n + 1];
    float a0 = 0.f, a1 = 0.f, a2 = 0.f;
    float d0 = 0.f, d1 = 0.f, d2 = 0.f;
    for (int base = lo; base < hi; base += 64) {
        int cnt = hi - base; if (cnt > 64) cnt = 64;
        int myeid = (lane < cnt) ? eids_p[base + lane] : 0;
        float4 myex = exv4[myeid];          // one independent load per lane
        int iters = (cnt + 1) >> 1;         // uniform trip count across wave
        for (int q = 0; q < iters; ++q) {
            int j = 2 * q + half;           // half 0: even edges, half 1: odd edges
            bool ok = (j < cnt);
            float ex0 = __shfl(myex.x, j);
            float ex1 = __shfl(myex.y, j);
            float ex2 = __shfl(myex.z, j);
            int   s   = __shfl(__float_as_int(myex.w), j);
            if (ok) {
                float x0 = xl[(long)s * HNO + k];
                float x1 = xl[(long)s * HNO + k + 32];
                float x2 = xl[(long)s * HNO + k + 64];
                a0 += ex0 * x0; a1 += ex1 * x1; a2 += ex2 * x2;
                d0 += ex0;      d1 += ex1;      d2 += ex2;
            }
        }
    }
    // combine the two halves
    a0 += __shfl_xor(a0, 32); a1 += __shfl_xor(a1, 32); a2 += __shfl_xor(a2, 32);
    d0 += __shfl_xor(d0, 32); d1 += __shfl_xor(d1, 32); d2 += __shfl_xor(d2, 32);
    // gat_out features (lane k holds in[k], in[32+k], in[64+k], in[96+k])
    float g0 = (d0 > 0.f ? a0 / d0 : 0.f) + bias_gat[k];
    float g1 = (d1 > 0.f ? a1 / d1 : 0.f) + bias_gat[32 + k];
    float g2 = (d2 > 0.f ? a2 / d2 : 0.f) + bias_gat[64 + k];
    float gg = glob[(long)batch[n] * GI + k];
    // fused node_mlp_2: out[k] = relu(b + sum_i in[i] * W[i][k]); halves split i-range
    float acc = 0.f;
    #pragma unroll
    for (int q = 0; q < 16; ++q) {
        int i2 = half * 16 + q;
        float v0 = __shfl(g0, i2);
        float v1 = __shfl(g1, i2);
        float v2 = __shfl(g2, i2);
        float v3 = __shfl(gg, i2);
        acc += v0 * sW[i2 * 32 + k] + v1 * sW[(32 + i2) * 32 + k]
             + v2 * sW[(64 + i2) * 32 + k] + v3 * sW[(96 + i2) * 32 + k];
    }
    acc += __shfl_xor(acc, 32);
    if (half == 0) x_new[n * NO + k] = fmaxf(acc + b_n2[k], 0.f);
}

// ---------------- K3: per-graph mean of x_new (batch sorted), then global MLP ----------------
__device__ __forceinline__ int lower_bound_dev(const int* __restrict__ a, int n, int v) {
    int lo = 0, hi = n;
    while (lo < hi) { int mid = (lo + hi) >> 1; if (a[mid] < v) lo = mid + 1; else hi = mid; }
    return lo;
}

__global__ __launch_bounds__(256) void k3_global(
    const float* __restrict__ x_new, const int* __restrict__ batch,
    const float* __restrict__ glob, const float* __restrict__ W_g,
    const float* __restrict__ b_g, float* __restrict__ u_new)
{
    __shared__ int s_lo, s_hi;
    __shared__ float s_part[8][32];
    __shared__ float s_mean[32];
    int g = blockIdx.x;
    if (threadIdx.x == 0) {
        s_lo = lower_bound_dev(batch, N_NODES, g);
        s_hi = lower_bound_dev(batch, N_NODES, g + 1);
    }
    __syncthreads();
    int lo = s_lo, hi = s_hi;
    int k = threadIdx.x & 31, c = threadIdx.x >> 5;
    float acc = 0.f;
    for (long n = lo + c; n < hi; n += 8) acc += x_new[n * NO + k];
    s_part[c][k] = acc;
    __syncthreads();
    if (threadIdx.x < 32) {
        float s = 0.f;
        #pragma unroll
        for (int c2 = 0; c2 < 8; ++c2) s += s_part[c2][k];
        int cnt = hi - lo;
        s_mean[k] = s / (float)(cnt > 0 ? cnt : 1);
    }
    __syncthreads();
    if (threadIdx.x < 32) {
        float acc2 = b_g[k];
        #pragma unroll
        for (int i = 0; i < 32; ++i) acc2 += glob[g * GI + i] * W_g[i * GO + k];
        #pragma unroll
        for (int i = 0; i < 32; ++i) acc2 += s_mean[i] * W_g[(32 + i) * GO + k];
        u_new[g * GO + k] = fmaxf(acc2, 0.f);
    }
}

extern "C" void kernel_launch(void* const* d_in, const int* in_sizes, int n_in,
                              void* d_out, int out_size, void* d_ws, size_t ws_size,
                              hipStream_t stream) {
    const float* x        = (const float*)d_in[0];
    const float* edge_attr= (const float*)d_in[1];
    const float* glob     = (const float*)d_in[2];
    const float* W_edge   = (const float*)d_in[3];
    const float* b_edge   = (const float*)d_in[4];
    const float* W_l      = (const float*)d_in[5];
    const float* b_l      = (const float*)d_in[6];
    const float* W_r      = (const float*)d_in[7];
    const float* b_r      = (const float*)d_in[8];
    const float* W_e      = (const float*)d_in[9];
    const float* att      = (const float*)d_in[10];
    const float* bias_gat = (const float*)d_in[11];
    const float* W_n2     = (const float*)d_in[12];
    const float* b_n2     = (const float*)d_in[13];
    const float* W_g      = (const float*)d_in[14];
    const float* b_g      = (const float*)d_in[15];
    const int* edge_index = (const int*)d_in[16];
    const int* batch      = (const int*)d_in[17];

    float* out   = (float*)d_out;
    float* x_new = out;                                    // N*32
    float* e_out = out + (size_t)N_NODES * NO;             // E*32
    float* u_new = e_out + (size_t)N_EDGES * EO;           // B*32

    // workspace layout (16B-aligned chunks first)
    float*  ws    = (float*)d_ws;
    float*  xl    = ws;                                    // N*96 floats  (38.4 MB)
    float*  xr    = xl + (size_t)N_NODES * HNO;            // N*96 floats  (38.4 MB)
    float4* exv4  = (float4*)(xr + (size_t)N_NODES * HNO); // E float4     (25.6 MB)
    int*    cnt   = (int*)(exv4 + (size_t)N_EDGES);        // N ints
    int*    off   = cnt + N_NODES;                         // N+1 ints
    int*    cursor= off + N_NODES + 1;                     // N ints
    int*    eids_p= cursor + N_NODES;                      // E ints       (6.4 MB)

    hipMemsetAsync(cnt, 0, (size_t)N_NODES * sizeof(int), stream);

    // CSR build (only needs edge_index)
    k_hist<<<1024, 256, 0, stream>>>(edge_index, cnt);

    int grid0 = 1024;
    int groups0 = (N_NODES + 7) / 8;
    int it0 = (groups0 + grid0 - 1) / grid0;
    k0_node_transform<<<grid0, 256, 0, stream>>>(x, W_l, b_l, W_r, b_r, xl, xr, it0);

    int grid1 = 2048;
    int groups1 = (N_EDGES + 7) / 8;
    int it1 = (groups1 + grid1 - 1) / grid1;
    k1a_edge<<<grid1, 256, 0, stream>>>(x, edge_attr, W_edge, b_edge, W_e, att,
                                        edge_index, xl, xr, e_out, exv4, it1);

    k_scan<<<1, 1024, 0, stream>>>(cnt, off, cursor);
    k_scatter<<<1024, 256, 0, stream>>>(edge_index, cursor, eids_p);

    int grid1b = (N_NODES + 3) / 4;   // one wave per node
    k1b_gather<<<grid1b, 256, 0, stream>>>(xl, exv4, eids_p, off, bias_gat, glob,
                                           batch, W_n2, b_n2, x_new);

    k3_global<<<NB, 256, 0, stream>>>(x_new, batch, glob, W_g, b_g, u_new);
}

// Round 4
// 1701.167 us; speedup vs baseline: 1.2976x; 1.2976x over previous
//
#include <hip/hip_runtime.h>

#define N_NODES 100000
#define N_EDGES 1600000
#define NB 64
#define NI 64
#define EI 32
#define GI 32
#define NO 32
#define EO 32
#define GO 32
#define HH 3
#define HNO 96   /* H*NO */
#define NEG 0.2f

// ---------------- K0: xl = x@W_l + b_l, xr = x@W_r + b_r  [N,96] each ----------------
__global__ __launch_bounds__(256) void k0_node_transform(
    const float* __restrict__ x, const float* __restrict__ W_l, const float* __restrict__ b_l,
    const float* __restrict__ W_r, const float* __restrict__ b_r,
    float* __restrict__ xl, float* __restrict__ xr, int niters)
{
    __shared__ float sWl[NI * HNO];   // 24 KB
    __shared__ float sWr[NI * HNO];   // 24 KB
    __shared__ float sx[8][NI];       // 2 KB
    int t = threadIdx.x;
    for (int f = t; f < NI * HNO; f += 256) { sWl[f] = W_l[f]; sWr[f] = W_r[f]; }
    __syncthreads();
    int k = t & 31, ni = t >> 5;
    float bl0 = b_l[k], bl1 = b_l[k + 32], bl2 = b_l[k + 64];
    float br0 = b_r[k], br1 = b_r[k + 32], br2 = b_r[k + 64];
    for (int it = 0; it < niters; ++it) {
        long g = (long)blockIdx.x + (long)it * gridDim.x;
        long n = g * 8 + ni;
        long nc = (n < N_NODES) ? n : 0;
        sx[ni][k]      = x[nc * NI + k];
        sx[ni][k + 32] = x[nc * NI + k + 32];
        __syncthreads();
        float al0 = bl0, al1 = bl1, al2 = bl2;
        float ar0 = br0, ar1 = br1, ar2 = br2;
        #pragma unroll 8
        for (int i = 0; i < NI; ++i) {
            float xv = sx[ni][i];
            al0 += xv * sWl[i * HNO + k];
            al1 += xv * sWl[i * HNO + k + 32];
            al2 += xv * sWl[i * HNO + k + 64];
            ar0 += xv * sWr[i * HNO + k];
            ar1 += xv * sWr[i * HNO + k + 32];
            ar2 += xv * sWr[i * HNO + k + 64];
        }
        if (n < N_NODES) {
            xl[n * HNO + k]      = al0; xl[n * HNO + k + 32] = al1; xl[n * HNO + k + 64] = al2;
            xr[n * HNO + k]      = ar0; xr[n * HNO + k + 32] = ar1; xr[n * HNO + k + 64] = ar2;
        }
        __syncthreads();
    }
}

// ---------------- K0b: pre_e[n][32] = b_edge + x[n] @ W_edge[0:64,:] ----------------
__global__ __launch_bounds__(256) void k0b_pre_edge(
    const float* __restrict__ x, const float* __restrict__ W_edge,
    const float* __restrict__ b_edge, float* __restrict__ pre_e, int niters)
{
    __shared__ float sW[NI * 32];   // 8 KB (top 64 rows of W_edge)
    __shared__ float sx[8][NI];     // 2 KB
    int t = threadIdx.x;
    for (int f = t; f < NI * 32; f += 256) sW[f] = W_edge[f];
    __syncthreads();
    int k = t & 31, ni = t >> 5;
    float be = b_edge[k];
    for (int it = 0; it < niters; ++it) {
        long n = ((long)blockIdx.x + (long)it * gridDim.x) * 8 + ni;
        long nc = (n < N_NODES) ? n : 0;
        sx[ni][k]      = x[nc * NI + k];
        sx[ni][k + 32] = x[nc * NI + k + 32];
        __syncthreads();
        float acc = be;
        #pragma unroll 8
        for (int i = 0; i < NI; ++i) acc += sx[ni][i] * sW[i * 32 + k];
        if (n < N_NODES) pre_e[n * 32 + k] = acc;
        __syncthreads();
    }
}

// ---------------- K_hist: cnt[dst]++ ----------------
__global__ __launch_bounds__(256) void k_hist(const int* __restrict__ eidx, int* __restrict__ cnt)
{
    long i = (long)blockIdx.x * 256 + threadIdx.x;
    long stride = (long)gridDim.x * 256;
    for (; i < N_EDGES; i += stride)
        atomicAdd(&cnt[eidx[N_EDGES + i]], 1);
}

// ---------------- K_scan: exclusive scan of cnt -> off (N+1) and cursor ----------------
__global__ __launch_bounds__(1024) void k_scan(const int* __restrict__ cnt,
                                               int* __restrict__ off, int* __restrict__ cursor)
{
    __shared__ int ssum[1024];
    const int CH = (N_NODES + 1023) / 1024;   // 98
    int t = threadIdx.x;
    int c0 = t * CH;
    int c1 = c0 + CH; if (c1 > N_NODES) c1 = N_NODES;
    int s = 0;
    for (int i = c0; i < c1; ++i) s += cnt[i];
    ssum[t] = s;
    __syncthreads();
    // Hillis-Steele inclusive scan
    for (int ofs = 1; ofs < 1024; ofs <<= 1) {
        int v = (t >= ofs) ? ssum[t - ofs] : 0;
        __syncthreads();
        ssum[t] += v;
        __syncthreads();
    }
    int run = ssum[t] - s;    // exclusive base for this chunk
    for (int i = c0; i < c1; ++i) {
        off[i] = run; cursor[i] = run;
        run += cnt[i];
    }
    if (t == 1023) off[N_NODES] = ssum[1023];
}

// ---------------- K_scatter: CSR edge-id + src-id lists grouped by dst ----------------
__global__ __launch_bounds__(256) void k_scatter(const int* __restrict__ eidx,
                                                 int* __restrict__ cursor,
                                                 int* __restrict__ eids_p,
                                                 int* __restrict__ srcs_p)
{
    long i = (long)blockIdx.x * 256 + threadIdx.x;
    long stride = (long)gridDim.x * 256;
    for (; i < N_EDGES; i += stride) {
        int s = eidx[i];
        int d = eidx[N_EDGES + i];
        int pos = atomicAdd(&cursor[d], 1);
        eids_p[pos] = (int)i;
        srcs_p[pos] = s;
    }
}

// ---------------- KF: dst-ordered fused edge pass + aggregate + node_mlp_2 ----------------
// One 32-lane group per dst node. Per edge (CSR order):
//   eo  = relu(pre_e[src] + ea[e] @ W_edge[64:96,:])   -> e_out[e]
//   h_j = xl[src] + xr[dst] + eo @ W_e                 (j = head)
//   p_j = sum_k leakyrelu(h_j)*att_j  (width-32 xor reduce); ex_j = exp(p_j)
//   a_j += ex_j * xl_j ; d_j += ex_j   (registers, no atomics)
// Tail: g = a/d + bias_gat; x_new[n] = relu([g, glob[batch[n]]] @ W_n2 + b_n2)
// No block barriers inside the node loop: LDS staging is wave-private (gid-indexed),
// write-then-read within the same wave is ordered by the DS pipe.
__global__ __launch_bounds__(256) void kF(
    const float* __restrict__ pre_e, const float* __restrict__ ea,
    const float* __restrict__ W_edge, const float* __restrict__ W_e,
    const float* __restrict__ att,
    const float* __restrict__ xl, const float* __restrict__ xr,
    const int* __restrict__ eids_p, const int* __restrict__ srcs_p,
    const int* __restrict__ off,
    const float* __restrict__ bias_gat, const float* __restrict__ glob,
    const int* __restrict__ batch, const float* __restrict__ W_n2,
    const float* __restrict__ b_n2,
    float* __restrict__ e_out, float* __restrict__ x_new, int niters)
{
    __shared__ float sW2[32 * 32];    // 4 KB  W_edge rows 64..95
    __shared__ float sWe[32 * 96];    // 12 KB
    __shared__ float sWn[128 * 32];   // 16 KB
    __shared__ float sAtt[96];
    __shared__ float sEa[8][32];      // 1 KB  per-group staging
    __shared__ float sEo[8][32];      // 1 KB
    __shared__ float sG[8][128];      // 4 KB
    int t = threadIdx.x;
    for (int f = t; f < 32 * 32; f += 256) sW2[f] = W_edge[64 * 32 + f];
    for (int f = t; f < 32 * 96; f += 256) sWe[f] = W_e[f];
    for (int f = t; f < 128 * 32; f += 256) sWn[f] = W_n2[f];
    if (t < 96) sAtt[t] = att[t];
    __syncthreads();
    int k = t & 31, gid = t >> 5;
    for (int it = 0; it < niters; ++it) {
        long n = ((long)blockIdx.x + (long)it * gridDim.x) * 8 + gid;
        if (n < N_NODES) {
            int lo = off[n], hi = off[n + 1];
            float xr0 = xr[n * HNO + k];
            float xr1 = xr[n * HNO + k + 32];
            float xr2 = xr[n * HNO + k + 64];
            float a0 = 0.f, a1 = 0.f, a2 = 0.f;
            float d0 = 0.f, d1 = 0.f, d2 = 0.f;
            // 2-deep pipeline: ids 2 ahead, data 1 ahead
            int e0 = 0, e1 = 0, s1 = 0;
            float pe_c = 0.f, eav_c = 0.f, xl0_c = 0.f, xl1_c = 0.f, xl2_c = 0.f;
            if (lo < hi) {
                e0 = eids_p[lo];
                int ss = srcs_p[lo];
                pe_c  = pre_e[(long)ss * 32 + k];
                eav_c = ea[(long)e0 * EI + k];
                xl0_c = xl[(long)ss * HNO + k];
                xl1_c = xl[(long)ss * HNO + k + 32];
                xl2_c = xl[(long)ss * HNO + k + 64];
                if (lo + 1 < hi) { e1 = eids_p[lo + 1]; s1 = srcs_p[lo + 1]; }
            }
            for (int pos = lo; pos < hi; ++pos) {
                // issue next-edge data loads (indices default 0 -> harmless)
                float pe_n  = pre_e[(long)s1 * 32 + k];
                float eav_n = ea[(long)e1 * EI + k];
                float xln0  = xl[(long)s1 * HNO + k];
                float xln1  = xl[(long)s1 * HNO + k + 32];
                float xln2  = xl[(long)s1 * HNO + k + 64];
                // prefetch ids 2 ahead
                int e2 = 0, s2 = 0;
                if (pos + 2 < hi) { e2 = eids_p[pos + 2]; s2 = srcs_p[pos + 2]; }
                // --- edge MLP on current edge ---
                sEa[gid][k] = eav_c;
                float acc = pe_c;
                #pragma unroll 8
                for (int i = 0; i < 32; ++i) acc += sEa[gid][i] * sW2[i * 32 + k];
                float eo = fmaxf(acc, 0.f);
                e_out[(long)e0 * EO + k] = eo;
                sEo[gid][k] = eo;
                // --- h, logits ---
                float h0 = xl0_c + xr0, h1 = xl1_c + xr1, h2 = xl2_c + xr2;
                #pragma unroll 8
                for (int i = 0; i < 32; ++i) {
                    float v = sEo[gid][i];
                    h0 += v * sWe[i * 96 + k];
                    h1 += v * sWe[i * 96 + 32 + k];
                    h2 += v * sWe[i * 96 + 64 + k];
                }
                float p0 = (h0 > 0.f ? h0 : NEG * h0) * sAtt[k];
                float p1 = (h1 > 0.f ? h1 : NEG * h1) * sAtt[32 + k];
                float p2 = (h2 > 0.f ? h2 : NEG * h2) * sAtt[64 + k];
                #pragma unroll
                for (int m = 1; m <= 16; m <<= 1) {
                    p0 += __shfl_xor(p0, m, 32);
                    p1 += __shfl_xor(p1, m, 32);
                    p2 += __shfl_xor(p2, m, 32);
                }
                float ex0 = __expf(p0), ex1 = __expf(p1), ex2 = __expf(p2);
                a0 += ex0 * xl0_c; a1 += ex1 * xl1_c; a2 += ex2 * xl2_c;
                d0 += ex0;         d1 += ex1;         d2 += ex2;
                // rotate pipeline
                e0 = e1; e1 = e2; s1 = s2;
                pe_c = pe_n; eav_c = eav_n;
                xl0_c = xln0; xl1_c = xln1; xl2_c = xln2;
            }
            // --- tail: gat features + fused node_mlp_2 ---
            float g0 = (d0 > 0.f ? a0 / d0 : 0.f) + bias_gat[k];
            float g1 = (d1 > 0.f ? a1 / d1 : 0.f) + bias_gat[32 + k];
            float g2 = (d2 > 0.f ? a2 / d2 : 0.f) + bias_gat[64 + k];
            float gg = glob[(long)batch[n] * GI + k];
            sG[gid][k] = g0; sG[gid][32 + k] = g1; sG[gid][64 + k] = g2; sG[gid][96 + k] = gg;
            float acc2 = b_n2[k];
            #pragma unroll 8
            for (int i = 0; i < 128; ++i) acc2 += sG[gid][i] * sWn[i * 32 + k];
            x_new[n * NO + k] = fmaxf(acc2, 0.f);
        }
    }
}

// ---------------- K3: per-graph mean of x_new (batch sorted), then global MLP ----------------
__device__ __forceinline__ int lower_bound_dev(const int* __restrict__ a, int n, int v) {
    int lo = 0, hi = n;
    while (lo < hi) { int mid = (lo + hi) >> 1; if (a[mid] < v) lo = mid + 1; else hi = mid; }
    return lo;
}

__global__ __launch_bounds__(256) void k3_global(
    const float* __restrict__ x_new, const int* __restrict__ batch,
    const float* __restrict__ glob, const float* __restrict__ W_g,
    const float* __restrict__ b_g, float* __restrict__ u_new)
{
    __shared__ int s_lo, s_hi;
    __shared__ float s_part[8][32];
    __shared__ float s_mean[32];
    int g = blockIdx.x;
    if (threadIdx.x == 0) {
        s_lo = lower_bound_dev(batch, N_NODES, g);
        s_hi = lower_bound_dev(batch, N_NODES, g + 1);
    }
    __syncthreads();
    int lo = s_lo, hi = s_hi;
    int k = threadIdx.x & 31, c = threadIdx.x >> 5;
    float acc = 0.f;
    for (long n = lo + c; n < hi; n += 8) acc += x_new[n * NO + k];
    s_part[c][k] = acc;
    __syncthreads();
    if (threadIdx.x < 32) {
        float s = 0.f;
        #pragma unroll
        for (int c2 = 0; c2 < 8; ++c2) s += s_part[c2][k];
        int cnt = hi - lo;
        s_mean[k] = s / (float)(cnt > 0 ? cnt : 1);
    }
    __syncthreads();
    if (threadIdx.x < 32) {
        float acc2 = b_g[k];
        #pragma unroll
        for (int i = 0; i < 32; ++i) acc2 += glob[g * GI + i] * W_g[i * GO + k];
        #pragma unroll
        for (int i = 0; i < 32; ++i) acc2 += s_mean[i] * W_g[(32 + i) * GO + k];
        u_new[g * GO + k] = fmaxf(acc2, 0.f);
    }
}

extern "C" void kernel_launch(void* const* d_in, const int* in_sizes, int n_in,
                              void* d_out, int out_size, void* d_ws, size_t ws_size,
                              hipStream_t stream) {
    const float* x        = (const float*)d_in[0];
    const float* edge_attr= (const float*)d_in[1];
    const float* glob     = (const float*)d_in[2];
    const float* W_edge   = (const float*)d_in[3];
    const float* b_edge   = (const float*)d_in[4];
    const float* W_l      = (const float*)d_in[5];
    const float* b_l      = (const float*)d_in[6];
    const float* W_r      = (const float*)d_in[7];
    const float* b_r      = (const float*)d_in[8];
    const float* W_e      = (const float*)d_in[9];
    const float* att      = (const float*)d_in[10];
    const float* bias_gat = (const float*)d_in[11];
    const float* W_n2     = (const float*)d_in[12];
    const float* b_n2     = (const float*)d_in[13];
    const float* W_g      = (const float*)d_in[14];
    const float* b_g      = (const float*)d_in[15];
    const int* edge_index = (const int*)d_in[16];
    const int* batch      = (const int*)d_in[17];

    float* out   = (float*)d_out;
    float* x_new = out;                                    // N*32
    float* e_out = out + (size_t)N_NODES * NO;             // E*32
    float* u_new = e_out + (size_t)N_EDGES * EO;           // B*32

    // workspace layout
    float*  ws    = (float*)d_ws;
    float*  xl    = ws;                                    // N*96 floats
    float*  xr    = xl + (size_t)N_NODES * HNO;            // N*96 floats
    float*  pre_e = xr + (size_t)N_NODES * HNO;            // N*32 floats
    int*    cnt   = (int*)(pre_e + (size_t)N_NODES * 32);  // N ints
    int*    off   = cnt + N_NODES;                         // N+1 ints
    int*    cursor= off + N_NODES + 1;                     // N ints
    int*    eids_p= cursor + N_NODES;                      // E ints
    int*    srcs_p= eids_p + N_EDGES;                      // E ints

    hipMemsetAsync(cnt, 0, (size_t)N_NODES * sizeof(int), stream);

    // CSR build
    k_hist<<<1024, 256, 0, stream>>>(edge_index, cnt);
    k_scan<<<1, 1024, 0, stream>>>(cnt, off, cursor);
    k_scatter<<<1024, 256, 0, stream>>>(edge_index, cursor, eids_p, srcs_p);

    int grid0 = 1024;
    int groups0 = (N_NODES + 7) / 8;                       // 12500
    int it0 = (groups0 + grid0 - 1) / grid0;
    k0_node_transform<<<grid0, 256, 0, stream>>>(x, W_l, b_l, W_r, b_r, xl, xr, it0);
    k0b_pre_edge<<<grid0, 256, 0, stream>>>(x, W_edge, b_edge, pre_e, it0);

    int gridF = 1024;
    int itF = (groups0 + gridF - 1) / gridF;               // 13
    kF<<<gridF, 256, 0, stream>>>(pre_e, edge_attr, W_edge, W_e, att, xl, xr,
                                  eids_p, srcs_p, off, bias_gat, glob, batch,
                                  W_n2, b_n2, e_out, x_new, itF);

    k3_global<<<NB, 256, 0, stream>>>(x_new, batch, glob, W_g, b_g, u_new);
}

// Round 6
// 1651.240 us; speedup vs baseline: 1.3368x; 1.0302x over previous
//
#include <hip/hip_runtime.h>

#define N_NODES 100000
#define N_EDGES 1600000
#define NB 64
#define NI 64
#define EI 32
#define GI 32
#define NO 32
#define EO 32
#define GO 32
#define HH 3
#define HNO 96   /* H*NO */
#define NEG 0.2f

// ---------------- KA: fused node transforms, register-blocked ----------------
// Per block-iteration: 64 nodes. 8 groups of 32 lanes; group g owns 8 nodes.
// Lane k accumulates 7 outputs per node (xl0..2, xr0..2, pre_e) over i=0..63:
// per i: 7 weight LDS reads + 8 broadcast x reads amortized over 56 FMAs.
// pre_e[n] = b_edge + x[n] @ W_edge[0:64,:]  (edge-MLP precursor)
__global__ __launch_bounds__(256) void kA_node(
    const float* __restrict__ x,
    const float* __restrict__ W_l, const float* __restrict__ b_l,
    const float* __restrict__ W_r, const float* __restrict__ b_r,
    const float* __restrict__ W_edge, const float* __restrict__ b_edge,
    float* __restrict__ xl, float* __restrict__ xr, float* __restrict__ pre_e,
    int niters)
{
    __shared__ float sWl[NI * HNO];   // 24 KB
    __shared__ float sWr[NI * HNO];   // 24 KB
    __shared__ float sWp[NI * 32];    // 8 KB  (W_edge rows 0..63)
    __shared__ float sx[64 * NI];     // 16 KB (64 nodes x 64 feats, node-major)
    int t = threadIdx.x;
    for (int f = t; f < NI * HNO; f += 256) { sWl[f] = W_l[f]; sWr[f] = W_r[f]; }
    for (int f = t; f < NI * 32; f += 256) sWp[f] = W_edge[f];
    __syncthreads();
    int k = t & 31, g = t >> 5;
    float bl0 = b_l[k], bl1 = b_l[k + 32], bl2 = b_l[k + 64];
    float br0 = b_r[k], br1 = b_r[k + 32], br2 = b_r[k + 64];
    float bpe = b_edge[k];
    const long NX = (long)N_NODES * NI;
    for (int it = 0; it < niters; ++it) {
        long nb = ((long)blockIdx.x + (long)it * gridDim.x) * 64;
        long base = nb * NI;
        for (int f = t; f < 64 * NI; f += 256) {
            long idx = base + f;
            sx[f] = x[idx < NX ? idx : 0];
        }
        __syncthreads();
        float aL0[8], aL1[8], aL2[8], aR0[8], aR1[8], aR2[8], aP[8];
        #pragma unroll
        for (int m = 0; m < 8; ++m) {
            aL0[m] = bl0; aL1[m] = bl1; aL2[m] = bl2;
            aR0[m] = br0; aR1[m] = br1; aR2[m] = br2;
            aP[m] = bpe;
        }
        const float* sxg = &sx[g * 8 * NI];
        for (int i = 0; i < NI; ++i) {
            float wl0 = sWl[i * HNO + k], wl1 = sWl[i * HNO + 32 + k], wl2 = sWl[i * HNO + 64 + k];
            float wr0 = sWr[i * HNO + k], wr1 = sWr[i * HNO + 32 + k], wr2 = sWr[i * HNO + 64 + k];
            float wp  = sWp[i * 32 + k];
            #pragma unroll
            for (int m = 0; m < 8; ++m) {
                float xv = sxg[m * NI + i];
                aL0[m] += xv * wl0; aL1[m] += xv * wl1; aL2[m] += xv * wl2;
                aR0[m] += xv * wr0; aR1[m] += xv * wr1; aR2[m] += xv * wr2;
                aP[m]  += xv * wp;
            }
        }
        #pragma unroll
        for (int m = 0; m < 8; ++m) {
            long n = nb + g * 8 + m;
            if (n < N_NODES) {
                xl[n * HNO + k]      = aL0[m];
                xl[n * HNO + 32 + k] = aL1[m];
                xl[n * HNO + 64 + k] = aL2[m];
                xr[n * HNO + k]      = aR0[m];
                xr[n * HNO + 32 + k] = aR1[m];
                xr[n * HNO + 64 + k] = aR2[m];
                pre_e[n * 32 + k]    = aP[m];
            }
        }
        __syncthreads();
    }
}

// ---------------- K_hist: cnt[dst]++ ----------------
__global__ __launch_bounds__(256) void k_hist(const int* __restrict__ eidx, int* __restrict__ cnt)
{
    long i = (long)blockIdx.x * 256 + threadIdx.x;
    long stride = (long)gridDim.x * 256;
    for (; i < N_EDGES; i += stride)
        atomicAdd(&cnt[eidx[N_EDGES + i]], 1);
}

// ---------------- K_scan: exclusive scan of cnt -> off (N+1) and cursor ----------------
__global__ __launch_bounds__(1024) void k_scan(const int* __restrict__ cnt,
                                               int* __restrict__ off, int* __restrict__ cursor)
{
    __shared__ int ssum[1024];
    const int CH = (N_NODES + 1023) / 1024;   // 98
    int t = threadIdx.x;
    int c0 = t * CH;
    int c1 = c0 + CH; if (c1 > N_NODES) c1 = N_NODES;
    int s = 0;
    for (int i = c0; i < c1; ++i) s += cnt[i];
    ssum[t] = s;
    __syncthreads();
    for (int ofs = 1; ofs < 1024; ofs <<= 1) {
        int v = (t >= ofs) ? ssum[t - ofs] : 0;
        __syncthreads();
        ssum[t] += v;
        __syncthreads();
    }
    int run = ssum[t] - s;
    for (int i = c0; i < c1; ++i) {
        off[i] = run; cursor[i] = run;
        run += cnt[i];
    }
    if (t == 1023) off[N_NODES] = ssum[1023];
}

// ---------------- K_scatter: CSR {eid, src} pairs grouped by dst ----------------
__global__ __launch_bounds__(256) void k_scatter(const int* __restrict__ eidx,
                                                 int* __restrict__ cursor,
                                                 int2* __restrict__ ep)
{
    long i = (long)blockIdx.x * 256 + threadIdx.x;
    long stride = (long)gridDim.x * 256;
    for (; i < N_EDGES; i += stride) {
        int s = eidx[i];
        int d = eidx[N_EDGES + i];
        int pos = atomicAdd(&cursor[d], 1);
        ep[pos] = make_int2((int)i, s);
    }
}

// ---------------- KF: dst-ordered fused edge pass + register aggregation ----------------
// One 32-lane group per dst node. Per edge (CSR order):
//   eo  = relu(pre_e[src] + ea[e] @ W_edge[64:96,:])   -> e_out[e]
//   h_j = xl[src] + xr[dst] + eo @ W_e
//   p_j = sum_k leakyrelu(h_j)*att_j (width-32 xor reduce); ex_j = exp(p_j)
//   a_j += ex_j * xl_j ; d_j += ex_j   (registers, no atomics)
// Tail writes g[n][96] = a/d + bias_gat (node_mlp_2 moved to K2 to keep LDS small:
// ~18.4 KB -> 8 blocks/CU for latency hiding).
__global__ __launch_bounds__(256) void kF(
    const float* __restrict__ pre_e, const float* __restrict__ ea,
    const float* __restrict__ W_edge, const float* __restrict__ W_e,
    const float* __restrict__ att,
    const float* __restrict__ xl, const float* __restrict__ xr,
    const int2* __restrict__ ep, const int* __restrict__ off,
    const float* __restrict__ bias_gat,
    float* __restrict__ e_out, float* __restrict__ g_out, int niters)
{
    __shared__ float sW2[32 * 32];    // 4 KB  W_edge rows 64..95
    __shared__ float sWe[32 * 96];    // 12 KB
    __shared__ float sEa[8][32];      // 1 KB  group-private staging
    __shared__ float sEo[8][32];      // 1 KB
    int t = threadIdx.x;
    for (int f = t; f < 32 * 32; f += 256) sW2[f] = W_edge[64 * 32 + f];
    for (int f = t; f < 32 * 96; f += 256) sWe[f] = W_e[f];
    __syncthreads();
    int k = t & 31, gid = t >> 5;
    float at0 = att[k], at1 = att[32 + k], at2 = att[64 + k];
    float bg0 = bias_gat[k], bg1 = bias_gat[32 + k], bg2 = bias_gat[64 + k];
    for (int it = 0; it < niters; ++it) {
        long n = ((long)blockIdx.x + (long)it * gridDim.x) * 8 + gid;
        if (n < N_NODES) {
            int lo = off[n], hi = off[n + 1];
            float xr0 = xr[n * HNO + k];
            float xr1 = xr[n * HNO + 32 + k];
            float xr2 = xr[n * HNO + 64 + k];
            float a0 = 0.f, a1 = 0.f, a2 = 0.f;
            float d0 = 0.f, d1 = 0.f, d2 = 0.f;
            // 2-deep pipeline: ids 2 ahead, data 1 ahead
            int e0 = 0, e1 = 0, s1 = 0;
            float pe_c = 0.f, eav_c = 0.f, xl0_c = 0.f, xl1_c = 0.f, xl2_c = 0.f;
            if (lo < hi) {
                int2 es = ep[lo];
                e0 = es.x;
                pe_c  = pre_e[(long)es.y * 32 + k];
                eav_c = ea[(long)e0 * EI + k];
                xl0_c = xl[(long)es.y * HNO + k];
                xl1_c = xl[(long)es.y * HNO + 32 + k];
                xl2_c = xl[(long)es.y * HNO + 64 + k];
                if (lo + 1 < hi) { int2 es1 = ep[lo + 1]; e1 = es1.x; s1 = es1.y; }
            }
            for (int pos = lo; pos < hi; ++pos) {
                // issue next-edge data loads (index 0 defaults are harmless)
                float pe_n  = pre_e[(long)s1 * 32 + k];
                float eav_n = ea[(long)e1 * EI + k];
                float xln0  = xl[(long)s1 * HNO + k];
                float xln1  = xl[(long)s1 * HNO + 32 + k];
                float xln2  = xl[(long)s1 * HNO + 64 + k];
                int e2 = 0, s2 = 0;
                if (pos + 2 < hi) { int2 es2 = ep[pos + 2]; e2 = es2.x; s2 = es2.y; }
                // --- edge MLP on current edge ---
                sEa[gid][k] = eav_c;
                float acc = pe_c;
                #pragma unroll 8
                for (int i = 0; i < 32; ++i) acc += sEa[gid][i] * sW2[i * 32 + k];
                float eo = fmaxf(acc, 0.f);
                e_out[(long)e0 * EO + k] = eo;
                sEo[gid][k] = eo;
                // --- h, logits ---
                float h0 = xl0_c + xr0, h1 = xl1_c + xr1, h2 = xl2_c + xr2;
                #pragma unroll 8
                for (int i = 0; i < 32; ++i) {
                    float v = sEo[gid][i];
                    h0 += v * sWe[i * 96 + k];
                    h1 += v * sWe[i * 96 + 32 + k];
                    h2 += v * sWe[i * 96 + 64 + k];
                }
                float p0 = (h0 > 0.f ? h0 : NEG * h0) * at0;
                float p1 = (h1 > 0.f ? h1 : NEG * h1) * at1;
                float p2 = (h2 > 0.f ? h2 : NEG * h2) * at2;
                #pragma unroll
                for (int m = 1; m <= 16; m <<= 1) {
                    p0 += __shfl_xor(p0, m, 32);
                    p1 += __shfl_xor(p1, m, 32);
                    p2 += __shfl_xor(p2, m, 32);
                }
                float ex0 = __expf(p0), ex1 = __expf(p1), ex2 = __expf(p2);
                a0 += ex0 * xl0_c; a1 += ex1 * xl1_c; a2 += ex2 * xl2_c;
                d0 += ex0;         d1 += ex1;         d2 += ex2;
                // rotate pipeline
                e0 = e1; e1 = e2; s1 = s2;
                pe_c = pe_n; eav_c = eav_n;
                xl0_c = xln0; xl1_c = xln1; xl2_c = xln2;
            }
            g_out[n * HNO + k]      = (d0 > 0.f ? a0 / d0 : 0.f) + bg0;
            g_out[n * HNO + 32 + k] = (d1 > 0.f ? a1 / d1 : 0.f) + bg1;
            g_out[n * HNO + 64 + k] = (d2 > 0.f ? a2 / d2 : 0.f) + bg2;
        }
    }
}

// ---------------- K2: x_new = relu([g, glob[batch]] @ W_n2 + b_n2) ----------------
__global__ __launch_bounds__(256) void k2_node_out(
    const float* __restrict__ g, const float* __restrict__ glob,
    const int* __restrict__ batch, const float* __restrict__ W_n2,
    const float* __restrict__ b_n2, float* __restrict__ x_new, int niters)
{
    __shared__ float sW[128 * 32];   // 16 KB
    __shared__ float sIn[8][128];    // 4 KB
    int t = threadIdx.x;
    for (int f = t; f < 128 * 32; f += 256) sW[f] = W_n2[f];
    __syncthreads();
    int k = t & 31, ni = t >> 5;
    float bn = b_n2[k];
    for (int it = 0; it < niters; ++it) {
        long n = ((long)blockIdx.x + (long)it * gridDim.x) * 8 + ni;
        long nc = (n < N_NODES) ? n : 0;
        #pragma unroll
        for (int r = 0; r < 3; ++r) {
            int j = r * 32 + k;
            sIn[ni][j] = g[nc * HNO + j];
        }
        sIn[ni][96 + k] = glob[(long)batch[nc] * GI + k];
        __syncthreads();
        float acc = bn;
        #pragma unroll 8
        for (int i = 0; i < 128; ++i) acc += sIn[ni][i] * sW[i * 32 + k];
        if (n < N_NODES) x_new[n * NO + k] = fmaxf(acc, 0.f);
        __syncthreads();
    }
}

// ---------------- K3: per-graph mean of x_new (batch sorted), then global MLP ----------------
__device__ __forceinline__ int lower_bound_dev(const int* __restrict__ a, int n, int v) {
    int lo = 0, hi = n;
    while (lo < hi) { int mid = (lo + hi) >> 1; if (a[mid] < v) lo = mid + 1; else hi = mid; }
    return lo;
}

__global__ __launch_bounds__(256) void k3_global(
    const float* __restrict__ x_new, const int* __restrict__ batch,
    const float* __restrict__ glob, const float* __restrict__ W_g,
    const float* __restrict__ b_g, float* __restrict__ u_new)
{
    __shared__ int s_lo, s_hi;
    __shared__ float s_part[8][32];
    __shared__ float s_mean[32];
    int g = blockIdx.x;
    if (threadIdx.x == 0) {
        s_lo = lower_bound_dev(batch, N_NODES, g);
        s_hi = lower_bound_dev(batch, N_NODES, g + 1);
    }
    __syncthreads();
    int lo = s_lo, hi = s_hi;
    int k = threadIdx.x & 31, c = threadIdx.x >> 5;
    float acc = 0.f;
    for (long n = lo + c; n < hi; n += 8) acc += x_new[n * NO + k];
    s_part[c][k] = acc;
    __syncthreads();
    if (threadIdx.x < 32) {
        float s = 0.f;
        #pragma unroll
        for (int c2 = 0; c2 < 8; ++c2) s += s_part[c2][k];
        int cnt = hi - lo;
        s_mean[k] = s / (float)(cnt > 0 ? cnt : 1);
    }
    __syncthreads();
    if (threadIdx.x < 32) {
        float acc2 = b_g[k];
        #pragma unroll
        for (int i = 0; i < 32; ++i) acc2 += glob[g * GI + i] * W_g[i * GO + k];
        #pragma unroll
        for (int i = 0; i < 32; ++i) acc2 += s_mean[i] * W_g[(32 + i) * GO + k];
        u_new[g * GO + k] = fmaxf(acc2, 0.f);
    }
}

extern "C" void kernel_launch(void* const* d_in, const int* in_sizes, int n_in,
                              void* d_out, int out_size, void* d_ws, size_t ws_size,
                              hipStream_t stream) {
    const float* x        = (const float*)d_in[0];
    const float* edge_attr= (const float*)d_in[1];
    const float* glob     = (const float*)d_in[2];
    const float* W_edge   = (const float*)d_in[3];
    const float* b_edge   = (const float*)d_in[4];
    const float* W_l      = (const float*)d_in[5];
    const float* b_l      = (const float*)d_in[6];
    const float* W_r      = (const float*)d_in[7];
    const float* b_r      = (const float*)d_in[8];
    const float* W_e      = (const float*)d_in[9];
    const float* att      = (const float*)d_in[10];
    const float* bias_gat = (const float*)d_in[11];
    const float* W_n2     = (const float*)d_in[12];
    const float* b_n2     = (const float*)d_in[13];
    const float* W_g      = (const float*)d_in[14];
    const float* b_g      = (const float*)d_in[15];
    const int* edge_index = (const int*)d_in[16];
    const int* batch      = (const int*)d_in[17];

    float* out   = (float*)d_out;
    float* x_new = out;                                    // N*32
    float* e_out = out + (size_t)N_NODES * NO;             // E*32
    float* u_new = e_out + (size_t)N_EDGES * EO;           // B*32

    // workspace layout (floats before ep sum to N*320 = 32M -> ep stays 8B-aligned)
    float*  ws    = (float*)d_ws;
    float*  xl    = ws;                                    // N*96
    float*  xr    = xl + (size_t)N_NODES * HNO;            // N*96
    float*  pre_e = xr + (size_t)N_NODES * HNO;            // N*32
    float*  g_buf = pre_e + (size_t)N_NODES * 32;          // N*96
    int2*   ep    = (int2*)(g_buf + (size_t)N_NODES * HNO);// E int2
    int*    cnt   = (int*)(ep + (size_t)N_EDGES);          // N
    int*    off   = cnt + N_NODES;                         // N+1
    int*    cursor= off + N_NODES + 1;                     // N

    hipMemsetAsync(cnt, 0, (size_t)N_NODES * sizeof(int), stream);

    // CSR build
    k_hist<<<1024, 256, 0, stream>>>(edge_index, cnt);
    k_scan<<<1, 1024, 0, stream>>>(cnt, off, cursor);
    k_scatter<<<1024, 256, 0, stream>>>(edge_index, cursor, ep);

    // node transforms (xl, xr, pre_e in one pass over x)
    int gridA = 1024;
    int groups64 = (N_NODES + 63) / 64;                    // 1563
    int itA = (groups64 + gridA - 1) / gridA;              // 2
    kA_node<<<gridA, 256, 0, stream>>>(x, W_l, b_l, W_r, b_r, W_edge, b_edge,
                                       xl, xr, pre_e, itA);

    // fused edge pass + aggregation
    int gridF = 2048;
    int groups8 = (N_NODES + 7) / 8;                       // 12500
    int itF = (groups8 + gridF - 1) / gridF;               // 7
    kF<<<gridF, 256, 0, stream>>>(pre_e, edge_attr, W_edge, W_e, att, xl, xr,
                                  ep, off, bias_gat, e_out, g_buf, itF);

    // node_mlp_2
    int grid2 = 1024;
    int it2 = (groups8 + grid2 - 1) / grid2;               // 13
    k2_node_out<<<grid2, 256, 0, stream>>>(g_buf, glob, batch, W_n2, b_n2, x_new, it2);

    k3_global<<<NB, 256, 0, stream>>>(x_new, batch, glob, W_g, b_g, u_new);
}

// Round 7
// 1260.751 us; speedup vs baseline: 1.7509x; 1.3097x over previous
//
#include <hip/hip_runtime.h>

#define N_NODES 100000
#define N_EDGES 1600000
#define NB 64
#define NI 64
#define EI 32
#define GI 32
#define NO 32
#define EO 32
#define GO 32
#define HH 3
#define HNO 96   /* H*NO */
#define NEG 0.2f
#define SCAN_BLKS 98   /* ceil(100000/1024) */

// ---------------- KA: fused node transforms, register-blocked ----------------
__global__ __launch_bounds__(256) void kA_node(
    const float* __restrict__ x,
    const float* __restrict__ W_l, const float* __restrict__ b_l,
    const float* __restrict__ W_r, const float* __restrict__ b_r,
    const float* __restrict__ W_edge, const float* __restrict__ b_edge,
    float* __restrict__ xl, float* __restrict__ xr, float* __restrict__ pre_e,
    int niters)
{
    __shared__ float sWl[NI * HNO];   // 24 KB
    __shared__ float sWr[NI * HNO];   // 24 KB
    __shared__ float sWp[NI * 32];    // 8 KB  (W_edge rows 0..63)
    __shared__ float sx[64 * NI];     // 16 KB
    int t = threadIdx.x;
    for (int f = t; f < NI * HNO; f += 256) { sWl[f] = W_l[f]; sWr[f] = W_r[f]; }
    for (int f = t; f < NI * 32; f += 256) sWp[f] = W_edge[f];
    __syncthreads();
    int k = t & 31, g = t >> 5;
    float bl0 = b_l[k], bl1 = b_l[k + 32], bl2 = b_l[k + 64];
    float br0 = b_r[k], br1 = b_r[k + 32], br2 = b_r[k + 64];
    float bpe = b_edge[k];
    const long NX = (long)N_NODES * NI;
    for (int it = 0; it < niters; ++it) {
        long nb = ((long)blockIdx.x + (long)it * gridDim.x) * 64;
        long base = nb * NI;
        for (int f = t; f < 64 * NI; f += 256) {
            long idx = base + f;
            sx[f] = x[idx < NX ? idx : 0];
        }
        __syncthreads();
        float aL0[8], aL1[8], aL2[8], aR0[8], aR1[8], aR2[8], aP[8];
        #pragma unroll
        for (int m = 0; m < 8; ++m) {
            aL0[m] = bl0; aL1[m] = bl1; aL2[m] = bl2;
            aR0[m] = br0; aR1[m] = br1; aR2[m] = br2;
            aP[m] = bpe;
        }
        const float* sxg = &sx[g * 8 * NI];
        for (int i = 0; i < NI; ++i) {
            float wl0 = sWl[i * HNO + k], wl1 = sWl[i * HNO + 32 + k], wl2 = sWl[i * HNO + 64 + k];
            float wr0 = sWr[i * HNO + k], wr1 = sWr[i * HNO + 32 + k], wr2 = sWr[i * HNO + 64 + k];
            float wp  = sWp[i * 32 + k];
            #pragma unroll
            for (int m = 0; m < 8; ++m) {
                float xv = sxg[m * NI + i];
                aL0[m] += xv * wl0; aL1[m] += xv * wl1; aL2[m] += xv * wl2;
                aR0[m] += xv * wr0; aR1[m] += xv * wr1; aR2[m] += xv * wr2;
                aP[m]  += xv * wp;
            }
        }
        #pragma unroll
        for (int m = 0; m < 8; ++m) {
            long n = nb + g * 8 + m;
            if (n < N_NODES) {
                xl[n * HNO + k]      = aL0[m];
                xl[n * HNO + 32 + k] = aL1[m];
                xl[n * HNO + 64 + k] = aL2[m];
                xr[n * HNO + k]      = aR0[m];
                xr[n * HNO + 32 + k] = aR1[m];
                xr[n * HNO + 64 + k] = aR2[m];
                pre_e[n * 32 + k]    = aP[m];
            }
        }
        __syncthreads();
    }
}

// ---------------- K_hist: cnt[dst]++ ----------------
__global__ __launch_bounds__(256) void k_hist(const int* __restrict__ eidx, int* __restrict__ cnt)
{
    long i = (long)blockIdx.x * 256 + threadIdx.x;
    long stride = (long)gridDim.x * 256;
    for (; i < N_EDGES; i += stride)
        atomicAdd(&cnt[eidx[N_EDGES + i]], 1);
}

// ---------------- parallel scan: per-block sums ----------------
__global__ __launch_bounds__(1024) void k_scan1(const int* __restrict__ cnt, int* __restrict__ bsum)
{
    __shared__ int s[1024];
    int i = blockIdx.x * 1024 + threadIdx.x;
    s[threadIdx.x] = (i < N_NODES) ? cnt[i] : 0;
    for (int o = 512; o > 0; o >>= 1) {
        __syncthreads();
        if (threadIdx.x < o) s[threadIdx.x] += s[threadIdx.x + o];
    }
    if (threadIdx.x == 0) bsum[blockIdx.x] = s[0];
}

// ---------------- scan of the 98 block sums -> exclusive bases (in place) ----------------
__global__ __launch_bounds__(128) void k_scan2(int* __restrict__ bsum)
{
    __shared__ int s[128];
    int v = (threadIdx.x < SCAN_BLKS) ? bsum[threadIdx.x] : 0;
    s[threadIdx.x] = v;
    for (int o = 1; o < 128; o <<= 1) {
        __syncthreads();
        int a = (threadIdx.x >= o) ? s[threadIdx.x - o] : 0;
        __syncthreads();
        s[threadIdx.x] += a;
    }
    if (threadIdx.x < SCAN_BLKS) bsum[threadIdx.x] = s[threadIdx.x] - v;  // exclusive base
}

// ---------------- per-block rescan + write off/cursor ----------------
__global__ __launch_bounds__(1024) void k_scan3(const int* __restrict__ cnt,
                                                const int* __restrict__ bsum,
                                                int* __restrict__ off, int* __restrict__ cursor)
{
    __shared__ int s[1024];
    int i = blockIdx.x * 1024 + threadIdx.x;
    int v = (i < N_NODES) ? cnt[i] : 0;
    s[threadIdx.x] = v;
    for (int o = 1; o < 1024; o <<= 1) {
        __syncthreads();
        int a = (threadIdx.x >= o) ? s[threadIdx.x - o] : 0;
        __syncthreads();
        s[threadIdx.x] += a;
    }
    int excl = bsum[blockIdx.x] + s[threadIdx.x] - v;
    if (i < N_NODES) {
        off[i] = excl; cursor[i] = excl;
        if (i == N_NODES - 1) off[N_NODES] = excl + v;
    }
}

// ---------------- K_scatter: CSR {eid, src} pairs grouped by dst ----------------
__global__ __launch_bounds__(256) void k_scatter(const int* __restrict__ eidx,
                                                 int* __restrict__ cursor,
                                                 int2* __restrict__ ep)
{
    long i = (long)blockIdx.x * 256 + threadIdx.x;
    long stride = (long)gridDim.x * 256;
    for (; i < N_EDGES; i += stride) {
        int s = eidx[i];
        int d = eidx[N_EDGES + i];
        int pos = atomicAdd(&cursor[d], 1);
        ep[pos] = make_int2((int)i, s);
    }
}

// ---------------- KF: dst-ordered fused edge pass, DUAL-EDGE per group ----------------
// One 32-lane group per dst node; each step processes 2 consecutive CSR edges (A,B).
// Shared weight reads (sW2/sWe) feed both edges' FMAs -> ~2x fewer instructions/edge
// and 2-way ILP on all serial chains. Register aggregation; no atomics.
__global__ __launch_bounds__(256) void kF(
    const float* __restrict__ pre_e, const float* __restrict__ ea,
    const float* __restrict__ W_edge, const float* __restrict__ W_e,
    const float* __restrict__ att,
    const float* __restrict__ xl, const float* __restrict__ xr,
    const int2* __restrict__ ep, const int* __restrict__ off,
    const float* __restrict__ bias_gat,
    float* __restrict__ e_out, float* __restrict__ g_out, int niters)
{
    __shared__ float sW2[32 * 32];    // 4 KB  W_edge rows 64..95
    __shared__ float sWe[32 * 96];    // 12 KB
    __shared__ float2 sEa2[8][32];    // 2 KB  dual staging (A,B) per group
    __shared__ float2 sEo2[8][32];    // 2 KB
    int t = threadIdx.x;
    for (int f = t; f < 32 * 32; f += 256) sW2[f] = W_edge[64 * 32 + f];
    for (int f = t; f < 32 * 96; f += 256) sWe[f] = W_e[f];
    __syncthreads();
    int k = t & 31, gid = t >> 5;
    float at0 = att[k], at1 = att[32 + k], at2 = att[64 + k];
    float bg0 = bias_gat[k], bg1 = bias_gat[32 + k], bg2 = bias_gat[64 + k];
    for (int it = 0; it < niters; ++it) {
        long n = ((long)blockIdx.x + (long)it * gridDim.x) * 8 + gid;
        if (n >= N_NODES) continue;
        int lo = off[n], hi = off[n + 1];
        float xr0 = xr[n * HNO + k];
        float xr1 = xr[n * HNO + 32 + k];
        float xr2 = xr[n * HNO + 64 + k];
        float a0 = 0.f, a1 = 0.f, a2 = 0.f;
        float d0 = 0.f, d1 = 0.f, d2 = 0.f;
        int deg = hi - lo;
        int steps = (deg + 1) >> 1;
        // current pair (A,B) data + next pair ids
        int eA = 0, sA = 0, eB = 0, sB = 0;
        int eA1 = 0, sA1 = 0, eB1 = 0, sB1 = 0;
        float peA = 0.f, peB = 0.f, eaA = 0.f, eaB = 0.f;
        float xlA0 = 0.f, xlA1 = 0.f, xlA2 = 0.f, xlB0 = 0.f, xlB1 = 0.f, xlB2 = 0.f;
        if (steps > 0) {
            int2 q = ep[lo]; eA = q.x; sA = q.y;
            if (lo + 1 < hi) { int2 r = ep[lo + 1]; eB = r.x; sB = r.y; }
            peA = pre_e[(long)sA * 32 + k];   peB = pre_e[(long)sB * 32 + k];
            eaA = ea[(long)eA * EI + k];      eaB = ea[(long)eB * EI + k];
            xlA0 = xl[(long)sA * HNO + k]; xlA1 = xl[(long)sA * HNO + 32 + k]; xlA2 = xl[(long)sA * HNO + 64 + k];
            xlB0 = xl[(long)sB * HNO + k]; xlB1 = xl[(long)sB * HNO + 32 + k]; xlB2 = xl[(long)sB * HNO + 64 + k];
            if (lo + 2 < hi) { int2 q1 = ep[lo + 2]; eA1 = q1.x; sA1 = q1.y; }
            if (lo + 3 < hi) { int2 r1 = ep[lo + 3]; eB1 = r1.x; sB1 = r1.y; }
        }
        for (int st = 0; st < steps; ++st) {
            // prefetch next-pair data (clamped-id defaults are harmless)
            float peA_n = pre_e[(long)sA1 * 32 + k], peB_n = pre_e[(long)sB1 * 32 + k];
            float eaA_n = ea[(long)eA1 * EI + k],    eaB_n = ea[(long)eB1 * EI + k];
            float xlA0n = xl[(long)sA1 * HNO + k], xlA1n = xl[(long)sA1 * HNO + 32 + k], xlA2n = xl[(long)sA1 * HNO + 64 + k];
            float xlB0n = xl[(long)sB1 * HNO + k], xlB1n = xl[(long)sB1 * HNO + 32 + k], xlB2n = xl[(long)sB1 * HNO + 64 + k];
            // ids for pair st+2
            int eA2 = 0, sA2 = 0, eB2 = 0, sB2 = 0;
            int pA2 = lo + 2 * st + 4;
            if (pA2 < hi)     { int2 q2 = ep[pA2];     eA2 = q2.x; sA2 = q2.y; }
            if (pA2 + 1 < hi) { int2 r2 = ep[pA2 + 1]; eB2 = r2.x; sB2 = r2.y; }
            // ---- edge MLP (dual) ----
            sEa2[gid][k] = make_float2(eaA, eaB);
            float accA = peA, accB = peB;
            #pragma unroll 8
            for (int i = 0; i < 32; ++i) {
                float2 ev = sEa2[gid][i];
                float w = sW2[i * 32 + k];
                accA += ev.x * w; accB += ev.y * w;
            }
            float eoA = fmaxf(accA, 0.f), eoB = fmaxf(accB, 0.f);
            bool okB = (lo + 2 * st + 1) < hi;
            e_out[(long)eA * EO + k] = eoA;
            if (okB) e_out[(long)eB * EO + k] = eoB;
            sEo2[gid][k] = make_float2(eoA, eoB);
            // ---- h = xl + xr + eo@We (dual) ----
            float hA0 = xlA0 + xr0, hA1 = xlA1 + xr1, hA2 = xlA2 + xr2;
            float hB0 = xlB0 + xr0, hB1 = xlB1 + xr1, hB2 = xlB2 + xr2;
            #pragma unroll 8
            for (int i = 0; i < 32; ++i) {
                float2 ov = sEo2[gid][i];
                float w0 = sWe[i * 96 + k], w1 = sWe[i * 96 + 32 + k], w2 = sWe[i * 96 + 64 + k];
                hA0 += ov.x * w0; hA1 += ov.x * w1; hA2 += ov.x * w2;
                hB0 += ov.y * w0; hB1 += ov.y * w1; hB2 += ov.y * w2;
            }
            float pA0 = (hA0 > 0.f ? hA0 : NEG * hA0) * at0;
            float pA1 = (hA1 > 0.f ? hA1 : NEG * hA1) * at1;
            float pA2v = (hA2 > 0.f ? hA2 : NEG * hA2) * at2;
            float pB0 = (hB0 > 0.f ? hB0 : NEG * hB0) * at0;
            float pB1 = (hB1 > 0.f ? hB1 : NEG * hB1) * at1;
            float pB2 = (hB2 > 0.f ? hB2 : NEG * hB2) * at2;
            #pragma unroll
            for (int m = 1; m <= 16; m <<= 1) {
                pA0 += __shfl_xor(pA0, m, 32); pA1 += __shfl_xor(pA1, m, 32); pA2v += __shfl_xor(pA2v, m, 32);
                pB0 += __shfl_xor(pB0, m, 32); pB1 += __shfl_xor(pB1, m, 32); pB2 += __shfl_xor(pB2, m, 32);
            }
            float exA0 = __expf(pA0), exA1 = __expf(pA1), exA2 = __expf(pA2v);
            float exB0 = 0.f, exB1 = 0.f, exB2 = 0.f;
            if (okB) { exB0 = __expf(pB0); exB1 = __expf(pB1); exB2 = __expf(pB2); }
            a0 += exA0 * xlA0; a1 += exA1 * xlA1; a2 += exA2 * xlA2;
            a0 += exB0 * xlB0; a1 += exB1 * xlB1; a2 += exB2 * xlB2;
            d0 += exA0 + exB0; d1 += exA1 + exB1; d2 += exA2 + exB2;
            // rotate pipeline
            eA = eA1; sA = sA1; eB = eB1; sB = sB1;
            eA1 = eA2; sA1 = sA2; eB1 = eB2; sB1 = sB2;
            peA = peA_n; peB = peB_n; eaA = eaA_n; eaB = eaB_n;
            xlA0 = xlA0n; xlA1 = xlA1n; xlA2 = xlA2n;
            xlB0 = xlB0n; xlB1 = xlB1n; xlB2 = xlB2n;
        }
        g_out[n * HNO + k]      = (d0 > 0.f ? a0 / d0 : 0.f) + bg0;
        g_out[n * HNO + 32 + k] = (d1 > 0.f ? a1 / d1 : 0.f) + bg1;
        g_out[n * HNO + 64 + k] = (d2 > 0.f ? a2 / d2 : 0.f) + bg2;
    }
}

// ---------------- K2: x_new = relu([g, glob[batch]] @ W_n2 + b_n2) ----------------
__global__ __launch_bounds__(256) void k2_node_out(
    const float* __restrict__ g, const float* __restrict__ glob,
    const int* __restrict__ batch, const float* __restrict__ W_n2,
    const float* __restrict__ b_n2, float* __restrict__ x_new, int niters)
{
    __shared__ float sW[128 * 32];   // 16 KB
    __shared__ float sIn[8][128];    // 4 KB
    int t = threadIdx.x;
    for (int f = t; f < 128 * 32; f += 256) sW[f] = W_n2[f];
    __syncthreads();
    int k = t & 31, ni = t >> 5;
    float bn = b_n2[k];
    for (int it = 0; it < niters; ++it) {
        long n = ((long)blockIdx.x + (long)it * gridDim.x) * 8 + ni;
        long nc = (n < N_NODES) ? n : 0;
        #pragma unroll
        for (int r = 0; r < 3; ++r) {
            int j = r * 32 + k;
            sIn[ni][j] = g[nc * HNO + j];
        }
        sIn[ni][96 + k] = glob[(long)batch[nc] * GI + k];
        __syncthreads();
        float acc = bn;
        #pragma unroll 8
        for (int i = 0; i < 128; ++i) acc += sIn[ni][i] * sW[i * 32 + k];
        if (n < N_NODES) x_new[n * NO + k] = fmaxf(acc, 0.f);
        __syncthreads();
    }
}

// ---------------- K3: per-graph mean of x_new (batch sorted), then global MLP ----------------
__device__ __forceinline__ int lower_bound_dev(const int* __restrict__ a, int n, int v) {
    int lo = 0, hi = n;
    while (lo < hi) { int mid = (lo + hi) >> 1; if (a[mid] < v) lo = mid + 1; else hi = mid; }
    return lo;
}

__global__ __launch_bounds__(256) void k3_global(
    const float* __restrict__ x_new, const int* __restrict__ batch,
    const float* __restrict__ glob, const float* __restrict__ W_g,
    const float* __restrict__ b_g, float* __restrict__ u_new)
{
    __shared__ int s_lo, s_hi;
    __shared__ float s_part[8][32];
    __shared__ float s_mean[32];
    int g = blockIdx.x;
    if (threadIdx.x == 0) {
        s_lo = lower_bound_dev(batch, N_NODES, g);
        s_hi = lower_bound_dev(batch, N_NODES, g + 1);
    }
    __syncthreads();
    int lo = s_lo, hi = s_hi;
    int k = threadIdx.x & 31, c = threadIdx.x >> 5;
    float acc = 0.f;
    for (long n = lo + c; n < hi; n += 8) acc += x_new[n * NO + k];
    s_part[c][k] = acc;
    __syncthreads();
    if (threadIdx.x < 32) {
        float s = 0.f;
        #pragma unroll
        for (int c2 = 0; c2 < 8; ++c2) s += s_part[c2][k];
        int cnt = hi - lo;
        s_mean[k] = s / (float)(cnt > 0 ? cnt : 1);
    }
    __syncthreads();
    if (threadIdx.x < 32) {
        float acc2 = b_g[k];
        #pragma unroll
        for (int i = 0; i < 32; ++i) acc2 += glob[g * GI + i] * W_g[i * GO + k];
        #pragma unroll
        for (int i = 0; i < 32; ++i) acc2 += s_mean[i] * W_g[(32 + i) * GO + k];
        u_new[g * GO + k] = fmaxf(acc2, 0.f);
    }
}

extern "C" void kernel_launch(void* const* d_in, const int* in_sizes, int n_in,
                              void* d_out, int out_size, void* d_ws, size_t ws_size,
                              hipStream_t stream) {
    const float* x        = (const float*)d_in[0];
    const float* edge_attr= (const float*)d_in[1];
    const float* glob     = (const float*)d_in[2];
    const float* W_edge   = (const float*)d_in[3];
    const float* b_edge   = (const float*)d_in[4];
    const float* W_l      = (const float*)d_in[5];
    const float* b_l      = (const float*)d_in[6];
    const float* W_r      = (const float*)d_in[7];
    const float* b_r      = (const float*)d_in[8];
    const float* W_e      = (const float*)d_in[9];
    const float* att      = (const float*)d_in[10];
    const float* bias_gat = (const float*)d_in[11];
    const float* W_n2     = (const float*)d_in[12];
    const float* b_n2     = (const float*)d_in[13];
    const float* W_g      = (const float*)d_in[14];
    const float* b_g      = (const float*)d_in[15];
    const int* edge_index = (const int*)d_in[16];
    const int* batch      = (const int*)d_in[17];

    float* out   = (float*)d_out;
    float* x_new = out;                                    // N*32
    float* e_out = out + (size_t)N_NODES * NO;             // E*32
    float* u_new = e_out + (size_t)N_EDGES * EO;           // B*32

    // workspace layout (floats before ep sum to N*320 -> ep stays 8B-aligned)
    float*  ws    = (float*)d_ws;
    float*  xl    = ws;                                    // N*96
    float*  xr    = xl + (size_t)N_NODES * HNO;            // N*96
    float*  pre_e = xr + (size_t)N_NODES * HNO;            // N*32
    float*  g_buf = pre_e + (size_t)N_NODES * 32;          // N*96
    int2*   ep    = (int2*)(g_buf + (size_t)N_NODES * HNO);// E int2
    int*    cnt   = (int*)(ep + (size_t)N_EDGES);          // N
    int*    off   = cnt + N_NODES;                         // N+1
    int*    cursor= off + N_NODES + 1;                     // N
    int*    bsum  = cursor + N_NODES;                      // 128

    hipMemsetAsync(cnt, 0, (size_t)N_NODES * sizeof(int), stream);

    // CSR build (parallel scan)
    k_hist<<<1024, 256, 0, stream>>>(edge_index, cnt);
    k_scan1<<<SCAN_BLKS, 1024, 0, stream>>>(cnt, bsum);
    k_scan2<<<1, 128, 0, stream>>>(bsum);
    k_scan3<<<SCAN_BLKS, 1024, 0, stream>>>(cnt, bsum, off, cursor);
    k_scatter<<<1024, 256, 0, stream>>>(edge_index, cursor, ep);

    // node transforms (xl, xr, pre_e in one pass over x)
    int gridA = 1024;
    int groups64 = (N_NODES + 63) / 64;                    // 1563
    int itA = (groups64 + gridA - 1) / gridA;              // 2
    kA_node<<<gridA, 256, 0, stream>>>(x, W_l, b_l, W_r, b_r, W_edge, b_edge,
                                       xl, xr, pre_e, itA);

    // fused edge pass + aggregation (dual-edge)
    int gridF = 2048;
    int groups8 = (N_NODES + 7) / 8;                       // 12500
    int itF = (groups8 + gridF - 1) / gridF;               // 7
    kF<<<gridF, 256, 0, stream>>>(pre_e, edge_attr, W_edge, W_e, att, xl, xr,
                                  ep, off, bias_gat, e_out, g_buf, itF);

    // node_mlp_2
    int grid2 = 1024;
    int it2 = (groups8 + grid2 - 1) / grid2;               // 13
    k2_node_out<<<grid2, 256, 0, stream>>>(g_buf, glob, batch, W_n2, b_n2, x_new, it2);

    k3_global<<<NB, 256, 0, stream>>>(x_new, batch, glob, W_g, b_g, u_new);
}